// Round 2
// baseline (465.598 us; speedup 1.0000x reference)
//
#include <hip/hip_runtime.h>

// Problem dims (fixed): B=8, L=128, H=768, R=24
#define BD   8
#define LD   128
#define HD   768
#define RD   24
#define H2D  384

// ---------------------------------------------------------------------------
// pool[b,h] = sum_l embed[b,l,h]*mask[b,l] / sum_l mask[b,l]
__global__ void pool_kernel(const float* __restrict__ embed,
                            const float* __restrict__ mask,
                            float* __restrict__ pool) {
    __shared__ float mrow[LD];
    __shared__ float msum_sh;
    const int b = blockIdx.x, tid = threadIdx.x;
    if (tid < LD) mrow[tid] = mask[b * LD + tid];
    __syncthreads();
    if (tid == 0) {
        float s = 0.f;
        for (int l = 0; l < LD; ++l) s += mrow[l];
        msum_sh = s;
    }
    __syncthreads();
    const float inv = 1.0f / msum_sh;
    for (int h = tid; h < HD; h += blockDim.x) {
        float acc = 0.f;
        const float* base = embed + (size_t)b * LD * HD + h;
        for (int l = 0; l < LD; ++l) acc += base[(size_t)l * HD] * mrow[l];
        pool[b * HD + h] = acc * inv;
    }
}

// ---------------------------------------------------------------------------
// rel_hidden = relu(pool @ W_hr + b_hr); stage1 = rel_hidden @ W_rj + b_rj
// one block per b, 384 threads
__global__ void relstage_kernel(const float* __restrict__ pool,
                                const float* __restrict__ W_hr, const float* __restrict__ b_hr,
                                const float* __restrict__ W_rj, const float* __restrict__ b_rj,
                                float* __restrict__ out_stage1) {
    __shared__ float prow[HD];
    __shared__ float rh[H2D];
    const int b = blockIdx.x, tid = threadIdx.x;
    for (int h = tid; h < HD; h += 384) prow[h] = pool[b * HD + h];
    __syncthreads();
    {
        const int n = tid;  // 0..383
        float acc = b_hr[n];
        for (int k = 0; k < HD; ++k) acc += prow[k] * W_hr[k * H2D + n];
        rh[n] = fmaxf(acc, 0.f);
    }
    __syncthreads();
    if (tid < RD) {
        float acc = b_rj[tid];
        for (int k = 0; k < H2D; ++k) acc += rh[k] * W_rj[k * RD + tid];
        out_stage1[b * RD + tid] = acc;
    }
}

// ---------------------------------------------------------------------------
// Tiled GEMM: out[m,n] = X[m,:] @ W[:,n]  (fp32 accum, fp32 out to ws)
// FUSE=0: X = embed (M x 768), K given
// FUSE=1: X[m,k] = (k<768) ? rel_emb[target_rel[m/L], k] : embed[m, k-768];
//         epilogue: relu(acc + bias[n])
// BM=BN=64, BK=16, 256 threads, 4x4 micro-tile
template <int FUSE>
__global__ void gemm_kernel(const float* __restrict__ embed,
                            const float* __restrict__ W,
                            const float* __restrict__ bias,
                            const float* __restrict__ rel_emb,
                            const int* __restrict__ target_rel,
                            float* __restrict__ out,
                            int K) {
    const int BM = 64, BN = 64, BK = 16;
    __shared__ float Xs[BK][BM];
    __shared__ float Ws[BK][BN];
    const int tid = threadIdx.x;
    const int bn0 = blockIdx.x * BN;
    const int bm0 = blockIdx.y * BM;
    const int N = HD;
    const int tr = tid >> 4, tc = tid & 15;
    const int xr = tid >> 2, xc = (tid & 3) * 4;   // X tile: 64 rows x 16 k
    const int wr = tid >> 4, wc = (tid & 15) * 4;  // W tile: 16 k x 64 n
    int relrow = 0;
    if (FUSE) relrow = target_rel[bm0 / LD];  // block spans a single batch b

    float acc[4][4] = {};
    for (int k0 = 0; k0 < K; k0 += BK) {
#pragma unroll
        for (int q = 0; q < 4; ++q) {
            const int k = k0 + xc + q;
            float v;
            if (FUSE) {
                v = (k < HD) ? rel_emb[relrow * HD + k]
                             : embed[(size_t)(bm0 + xr) * HD + (k - HD)];
            } else {
                v = embed[(size_t)(bm0 + xr) * HD + k];
            }
            Xs[xc + q][xr] = v;
        }
#pragma unroll
        for (int q = 0; q < 4; ++q) {
            Ws[wr][wc + q] = W[(size_t)(k0 + wr) * N + bn0 + wc + q];
        }
        __syncthreads();
#pragma unroll
        for (int kk = 0; kk < BK; ++kk) {
            float a[4], bv[4];
#pragma unroll
            for (int i = 0; i < 4; ++i) a[i] = Xs[kk][tr * 4 + i];
#pragma unroll
            for (int j = 0; j < 4; ++j) bv[j] = Ws[kk][tc * 4 + j];
#pragma unroll
            for (int i = 0; i < 4; ++i)
#pragma unroll
                for (int j = 0; j < 4; ++j) acc[i][j] += a[i] * bv[j];
        }
        __syncthreads();
    }
#pragma unroll
    for (int i = 0; i < 4; ++i) {
        const int row = bm0 + tr * 4 + i;
#pragma unroll
        for (int j = 0; j < 4; ++j) {
            const int col = bn0 + tc * 4 + j;
            float v = acc[i][j];
            if (FUSE) v = fmaxf(v + bias[col], 0.f);
            out[(size_t)row * N + col] = v;
        }
    }
}

// ---------------------------------------------------------------------------
// pred_corres[b,i,j] = sum_h relu(A[b,j,h] + C[b,i,h] + b_corr[h]) * W_gc[h] + b_gc
// grid(L/4, B), 256 threads = 4 waves; block handles 4 consecutive i; wave owns j's
__global__ void corres_kernel(const float* __restrict__ A, const float* __restrict__ C,
                              const float* __restrict__ b_corr, const float* __restrict__ W_gc,
                              const float* __restrict__ b_gc,
                              float* __restrict__ out) {
    const int b = blockIdx.y;
    const int i0 = blockIdx.x * 4;
    const int tid = threadIdx.x;
    const int lane = tid & 63;
    const int wave = tid >> 6;  // 0..3

    float wg[12], cb[4][12];
#pragma unroll
    for (int s = 0; s < 12; ++s) {
        const int h = lane + 64 * s;
        wg[s] = W_gc[h];
        const float bc = b_corr[h];
#pragma unroll
        for (int i = 0; i < 4; ++i)
            cb[i][s] = C[((size_t)(b * LD + i0 + i)) * HD + h] + bc;
    }
    const float bg = b_gc[0];

    for (int j = wave; j < LD; j += 4) {
        const float* arow = A + ((size_t)(b * LD + j)) * HD;
        float a[12];
#pragma unroll
        for (int s = 0; s < 12; ++s) a[s] = arow[lane + 64 * s];
        float sum[4] = {0.f, 0.f, 0.f, 0.f};
#pragma unroll
        for (int s = 0; s < 12; ++s) {
#pragma unroll
            for (int i = 0; i < 4; ++i)
                sum[i] += fmaxf(a[s] + cb[i][s], 0.f) * wg[s];
        }
#pragma unroll
        for (int off = 32; off > 0; off >>= 1) {
#pragma unroll
            for (int i = 0; i < 4; ++i) sum[i] += __shfl_down(sum[i], off, 64);
        }
        if (lane == 0) {
#pragma unroll
            for (int i = 0; i < 4; ++i)
                out[((size_t)(b * LD + i0 + i)) * LD + j] = sum[i] + bg;
        }
    }
}

// ---------------------------------------------------------------------------
// out[m, t] = H1[m,:] @ Wt[:,t] + bt[t]   (t = 0..2), one wave per row
__global__ void rowdot3_kernel(const float* __restrict__ H1, const float* __restrict__ Wt,
                               const float* __restrict__ bt, float* __restrict__ out) {
    const int m = blockIdx.x;
    const int lane = threadIdx.x;  // 64
    float s0 = 0.f, s1 = 0.f, s2 = 0.f;
#pragma unroll
    for (int ss = 0; ss < 12; ++ss) {
        const int h = lane + 64 * ss;
        const float hv = H1[(size_t)m * HD + h];
        s0 += hv * Wt[h * 3 + 0];
        s1 += hv * Wt[h * 3 + 1];
        s2 += hv * Wt[h * 3 + 2];
    }
    for (int off = 32; off > 0; off >>= 1) {
        s0 += __shfl_down(s0, off, 64);
        s1 += __shfl_down(s1, off, 64);
        s2 += __shfl_down(s2, off, 64);
    }
    if (lane == 0) {
        out[m * 3 + 0] = s0 + bt[0];
        out[m * 3 + 1] = s1 + bt[1];
        out[m * 3 + 2] = s2 + bt[2];
    }
}

// ---------------------------------------------------------------------------
extern "C" void kernel_launch(void* const* d_in, const int* in_sizes, int n_in,
                              void* d_out, int out_size, void* d_ws, size_t ws_size,
                              hipStream_t stream) {
    const float* embed   = (const float*)d_in[0];
    const float* mask    = (const float*)d_in[1];
    const int*   trel    = (const int*)d_in[2];
    const float* W_hr    = (const float*)d_in[3];
    const float* b_hr    = (const float*)d_in[4];
    const float* W_rj    = (const float*)d_in[5];
    const float* b_rj    = (const float*)d_in[6];
    const float* rel_emb = (const float*)d_in[7];
    const float* W_corr  = (const float*)d_in[8];
    const float* b_corr  = (const float*)d_in[9];
    const float* W_gc    = (const float*)d_in[10];
    const float* b_gc    = (const float*)d_in[11];
    const float* W_sh    = (const float*)d_in[12];
    const float* b_sh    = (const float*)d_in[13];
    const float* W_st    = (const float*)d_in[14];
    const float* b_st    = (const float*)d_in[15];
    const float* W_oh    = (const float*)d_in[16];
    const float* b_oh    = (const float*)d_in[17];
    const float* W_ot    = (const float*)d_in[18];
    const float* b_ot    = (const float*)d_in[19];
    float* out = (float*)d_out;

    float* ws   = (float*)d_ws;
    float* pool = ws;                        // 6144 floats
    float* A    = ws + 8192;                 // 786432
    float* Cm   = ws + 8192 + 786432;        // 786432
    float* H1   = ws + 8192 + 2 * 786432;    // 786432 (reused for subj then obj)

    // Output layout: stage1[192] | subj[3072] | obj[3072] | pred_corres[131072]
    pool_kernel<<<BD, 256, 0, stream>>>(embed, mask, pool);
    relstage_kernel<<<BD, 384, 0, stream>>>(pool, W_hr, b_hr, W_rj, b_rj, out);

    dim3 ggrid(HD / 64, (BD * LD) / 64);  // (12, 16)
    gemm_kernel<0><<<ggrid, 256, 0, stream>>>(embed, W_corr, nullptr, nullptr, nullptr, A, HD);
    gemm_kernel<0><<<ggrid, 256, 0, stream>>>(embed, W_corr + (size_t)HD * HD, nullptr, nullptr, nullptr, Cm, HD);
    corres_kernel<<<dim3(LD / 4, BD), 256, 0, stream>>>(A, Cm, b_corr, W_gc, b_gc, out + 6336);

    gemm_kernel<1><<<ggrid, 256, 0, stream>>>(embed, W_sh, b_sh, rel_emb, trel, H1, 2 * HD);
    rowdot3_kernel<<<BD * LD, 64, 0, stream>>>(H1, W_st, b_st, out + 192);
    gemm_kernel<1><<<ggrid, 256, 0, stream>>>(embed, W_oh, b_oh, rel_emb, trel, H1, 2 * HD);
    rowdot3_kernel<<<BD * LD, 64, 0, stream>>>(H1, W_ot, b_ot, out + 3264);
}

// Round 3
// 226.911 us; speedup vs baseline: 2.0519x; 2.0519x over previous
//
#include <hip/hip_runtime.h>
#include <hip/hip_bf16.h>

// Problem dims (fixed): B=8, L=128, H=768, R=24
#define BD   8
#define LD   128
#define HD   768
#define RD   24
#define H2D  384
#define NF   1536   // fused N (two heads side by side)

typedef __attribute__((ext_vector_type(8))) short bf16x8;
typedef __attribute__((ext_vector_type(4))) float f32x4;

__device__ __forceinline__ short f2bf(float f) {
    __hip_bfloat16 h = __float2bfloat16(f);
    return *reinterpret_cast<short*>(&h);
}

// ---------------------------------------------------------------------------
// Fused pool + rel head: pool[b] -> rel_hidden -> stage1 (out[0:192])
__global__ void pool_relstage_kernel(const float* __restrict__ embed,
                                     const float* __restrict__ mask,
                                     const float* __restrict__ W_hr, const float* __restrict__ b_hr,
                                     const float* __restrict__ W_rj, const float* __restrict__ b_rj,
                                     float* __restrict__ out_stage1) {
    __shared__ float mrow[LD];
    __shared__ float prow[HD];
    __shared__ float rh[H2D];
    __shared__ float msum_sh;
    const int b = blockIdx.x, tid = threadIdx.x;
    if (tid < LD) mrow[tid] = mask[b * LD + tid];
    __syncthreads();
    if (tid == 0) {
        float s = 0.f;
        for (int l = 0; l < LD; ++l) s += mrow[l];
        msum_sh = s;
    }
    __syncthreads();
    const float inv = 1.0f / msum_sh;
    for (int h = tid; h < HD; h += 384) {
        float acc = 0.f;
        const float* base = embed + (size_t)b * LD * HD + h;
        for (int l = 0; l < LD; ++l) acc += base[(size_t)l * HD] * mrow[l];
        prow[h] = acc * inv;
    }
    __syncthreads();
    {
        const int n = tid;  // 0..383
        float acc = b_hr[n];
        for (int k = 0; k < HD; ++k) acc += prow[k] * W_hr[k * H2D + n];
        rh[n] = fmaxf(acc, 0.f);
    }
    __syncthreads();
    if (tid < RD) {
        float acc = b_rj[tid];
        for (int k = 0; k < H2D; ++k) acc += rh[k] * W_rj[k * RD + tid];
        out_stage1[b * RD + tid] = acc;
    }
}

// ---------------------------------------------------------------------------
// MFMA GEMM, fused-N = 1536 output. 64x64 tile, 256 threads (4 waves, each 32x32).
// MODE 0: X = embed (K=768); W' col n<768 -> W0[k][n], else W1[k][n-768]. No epilogue.
// MODE 1: X = [rel_emb[trel[b]] || embed] (K=1536); same W select; epilogue relu(+bias).
template <int MODE>
__global__ __launch_bounds__(256) void mfma_gemm(
        const float* __restrict__ embed,
        const float* __restrict__ W0, const float* __restrict__ W1,
        const float* __restrict__ bias0, const float* __restrict__ bias1,
        const float* __restrict__ rel_emb, const int* __restrict__ trel,
        float* __restrict__ out, int K) {
    __shared__ __align__(16) short As[64][40];  // [m][k] bf16, pad 8
    __shared__ __align__(16) short Bs[64][40];  // [n][k] bf16 (W transposed), pad 8

    const int tid = threadIdx.x;
    const int bn0 = blockIdx.x * 64;
    const int bm0 = blockIdx.y * 64;

    const float* Wp;
    const float* bp = nullptr;
    int col0;
    if (bn0 < HD) { Wp = W0; col0 = bn0; if (MODE) bp = bias0; }
    else          { Wp = W1; col0 = bn0 - HD; if (MODE) bp = bias1; }

    int rel = 0;
    if (MODE) rel = trel[bm0 / LD];  // 64-row block lies within one batch

    // staging indices
    const int am = tid >> 2;          // 0..63 (m row)
    const int ak = (tid & 3) * 4;     // 0,4,8,12
    const int bn = tid & 63;          // n row in Bs
    const int bk = (tid >> 6) * 8;    // 0,8,16,24

    // compute indices
    const int lane = tid & 63;
    const int wv = tid >> 6;
    const int wm = (wv >> 1) * 32;
    const int wn = (wv & 1) * 32;
    const int fr = lane & 15;
    const int kq = (lane >> 4) * 8;

    f32x4 acc00 = {0.f, 0.f, 0.f, 0.f}, acc01 = acc00, acc10 = acc00, acc11 = acc00;

    const int nk = K >> 5;
    for (int kt = 0; kt < nk; ++kt) {
        const int k0 = kt << 5;
        // ---- global loads (before barrier; overlap with other waves' compute)
        float4 va0, va1;
        if (MODE == 0) {
            const float* arow = embed + (size_t)(bm0 + am) * HD + k0;
            va0 = *(const float4*)(arow + ak);
            va1 = *(const float4*)(arow + ak + 16);
        } else {
            if (k0 < HD) {
                const float* arow = rel_emb + (size_t)rel * HD + k0;
                va0 = *(const float4*)(arow + ak);
                va1 = *(const float4*)(arow + ak + 16);
            } else {
                const float* arow = embed + (size_t)(bm0 + am) * HD + (k0 - HD);
                va0 = *(const float4*)(arow + ak);
                va1 = *(const float4*)(arow + ak + 16);
            }
        }
        float vb[8];
#pragma unroll
        for (int j = 0; j < 8; ++j)
            vb[j] = Wp[(size_t)(k0 + bk + j) * HD + col0 + bn];

        __syncthreads();  // previous tile fully consumed
        {
            short4 s0 = { f2bf(va0.x), f2bf(va0.y), f2bf(va0.z), f2bf(va0.w) };
            short4 s1 = { f2bf(va1.x), f2bf(va1.y), f2bf(va1.z), f2bf(va1.w) };
            *(short4*)&As[am][ak]      = s0;
            *(short4*)&As[am][ak + 16] = s1;
            bf16x8 pb;
#pragma unroll
            for (int j = 0; j < 8; ++j) pb[j] = f2bf(vb[j]);
            *(bf16x8*)&Bs[bn][bk] = pb;
        }
        __syncthreads();

        bf16x8 a0 = *(bf16x8*)&As[wm + fr][kq];
        bf16x8 a1 = *(bf16x8*)&As[wm + 16 + fr][kq];
        bf16x8 b0 = *(bf16x8*)&Bs[wn + fr][kq];
        bf16x8 b1 = *(bf16x8*)&Bs[wn + 16 + fr][kq];
        acc00 = __builtin_amdgcn_mfma_f32_16x16x32_bf16(a0, b0, acc00, 0, 0, 0);
        acc01 = __builtin_amdgcn_mfma_f32_16x16x32_bf16(a0, b1, acc01, 0, 0, 0);
        acc10 = __builtin_amdgcn_mfma_f32_16x16x32_bf16(a1, b0, acc10, 0, 0, 0);
        acc11 = __builtin_amdgcn_mfma_f32_16x16x32_bf16(a1, b1, acc11, 0, 0, 0);
    }

    // epilogue: C/D layout col=lane&15, row=(lane>>4)*4+reg  [m89/m91]
    const int mq = (lane >> 4) * 4;
#pragma unroll
    for (int i = 0; i < 2; ++i) {
#pragma unroll
        for (int j = 0; j < 2; ++j) {
            f32x4 a = (i == 0) ? (j == 0 ? acc00 : acc01) : (j == 0 ? acc10 : acc11);
            const int ncol = bn0 + wn + j * 16 + fr;
#pragma unroll
            for (int r = 0; r < 4; ++r) {
                const int mrow = bm0 + wm + i * 16 + mq + r;
                float v = a[r];
                if (MODE) v = fmaxf(v + bp[col0 + wn + j * 16 + fr], 0.f);
                out[(size_t)mrow * NF + ncol] = v;
            }
        }
    }
}

// ---------------------------------------------------------------------------
// pred_corres[b,i,j] = sum_h relu(A[b,j,h] + C[b,i,h] + b_corr[h]) * W_gc[h] + b_gc
// AC buffer: row m=b*L+idx, A at cols [0,768), C at cols [768,1536)
__global__ void corres_kernel(const float* __restrict__ AC,
                              const float* __restrict__ b_corr, const float* __restrict__ W_gc,
                              const float* __restrict__ b_gc,
                              float* __restrict__ out) {
    const int b = blockIdx.y;
    const int i0 = blockIdx.x * 4;
    const int tid = threadIdx.x;
    const int lane = tid & 63;
    const int wave = tid >> 6;  // 0..3

    float wg[12], cb[4][12];
#pragma unroll
    for (int s = 0; s < 12; ++s) {
        const int h = lane + 64 * s;
        wg[s] = W_gc[h];
        const float bc = b_corr[h];
#pragma unroll
        for (int i = 0; i < 4; ++i)
            cb[i][s] = AC[((size_t)(b * LD + i0 + i)) * NF + HD + h] + bc;
    }
    const float bg = b_gc[0];

    for (int j = wave; j < LD; j += 4) {
        const float* arow = AC + ((size_t)(b * LD + j)) * NF;
        float a[12];
#pragma unroll
        for (int s = 0; s < 12; ++s) a[s] = arow[lane + 64 * s];
        float sum[4] = {0.f, 0.f, 0.f, 0.f};
#pragma unroll
        for (int s = 0; s < 12; ++s) {
#pragma unroll
            for (int i = 0; i < 4; ++i)
                sum[i] += fmaxf(a[s] + cb[i][s], 0.f) * wg[s];
        }
#pragma unroll
        for (int off = 32; off > 0; off >>= 1) {
#pragma unroll
            for (int i = 0; i < 4; ++i) sum[i] += __shfl_down(sum[i], off, 64);
        }
        if (lane == 0) {
#pragma unroll
            for (int i = 0; i < 4; ++i)
                out[((size_t)(b * LD + i0 + i)) * LD + j] = sum[i] + bg;
        }
    }
}

// ---------------------------------------------------------------------------
// subj[m,t] = H1[m,0:768]@W_st[:,t]+b_st[t]; obj[m,t] = H1[m,768:1536]@W_ot[:,t]+b_ot[t]
__global__ void rowdot3x2_kernel(const float* __restrict__ H1,
                                 const float* __restrict__ W_st, const float* __restrict__ b_st,
                                 const float* __restrict__ W_ot, const float* __restrict__ b_ot,
                                 float* __restrict__ out_subj, float* __restrict__ out_obj) {
    const int m = blockIdx.x;
    const int lane = threadIdx.x;  // 64
    float s[3] = {0.f, 0.f, 0.f}, o[3] = {0.f, 0.f, 0.f};
#pragma unroll
    for (int ss = 0; ss < 12; ++ss) {
        const int h = lane + 64 * ss;
        const float hs = H1[(size_t)m * NF + h];
        const float ho = H1[(size_t)m * NF + HD + h];
#pragma unroll
        for (int t = 0; t < 3; ++t) {
            s[t] += hs * W_st[h * 3 + t];
            o[t] += ho * W_ot[h * 3 + t];
        }
    }
    for (int off = 32; off > 0; off >>= 1) {
#pragma unroll
        for (int t = 0; t < 3; ++t) {
            s[t] += __shfl_down(s[t], off, 64);
            o[t] += __shfl_down(o[t], off, 64);
        }
    }
    if (lane == 0) {
#pragma unroll
        for (int t = 0; t < 3; ++t) {
            out_subj[m * 3 + t] = s[t] + b_st[t];
            out_obj[m * 3 + t]  = o[t] + b_ot[t];
        }
    }
}

// ---------------------------------------------------------------------------
extern "C" void kernel_launch(void* const* d_in, const int* in_sizes, int n_in,
                              void* d_out, int out_size, void* d_ws, size_t ws_size,
                              hipStream_t stream) {
    const float* embed   = (const float*)d_in[0];
    const float* mask    = (const float*)d_in[1];
    const int*   trel    = (const int*)d_in[2];
    const float* W_hr    = (const float*)d_in[3];
    const float* b_hr    = (const float*)d_in[4];
    const float* W_rj    = (const float*)d_in[5];
    const float* b_rj    = (const float*)d_in[6];
    const float* rel_emb = (const float*)d_in[7];
    const float* W_corr  = (const float*)d_in[8];
    const float* b_corr  = (const float*)d_in[9];
    const float* W_gc    = (const float*)d_in[10];
    const float* b_gc    = (const float*)d_in[11];
    const float* W_sh    = (const float*)d_in[12];
    const float* b_sh    = (const float*)d_in[13];
    const float* W_st    = (const float*)d_in[14];
    const float* b_st    = (const float*)d_in[15];
    const float* W_oh    = (const float*)d_in[16];
    const float* b_oh    = (const float*)d_in[17];
    const float* W_ot    = (const float*)d_in[18];
    const float* b_ot    = (const float*)d_in[19];
    float* out = (float*)d_out;

    // ws: one 1024x1536 fp32 buffer (6.3 MB), reused: AC (for corres), then H1.
    float* AC = (float*)d_ws;

    // Output layout: stage1[192] | subj[3072] | obj[3072] | pred_corres[131072]
    pool_relstage_kernel<<<BD, 384, 0, stream>>>(embed, mask, W_hr, b_hr, W_rj, b_rj, out);

    dim3 ggrid(NF / 64, (BD * LD) / 64);  // (24, 16) = 384 blocks
    mfma_gemm<0><<<ggrid, 256, 0, stream>>>(embed, W_corr, W_corr + (size_t)HD * HD,
                                            nullptr, nullptr, nullptr, nullptr, AC, HD);
    corres_kernel<<<dim3(LD / 4, BD), 256, 0, stream>>>(AC, b_corr, W_gc, b_gc, out + 6336);

    mfma_gemm<1><<<ggrid, 256, 0, stream>>>(embed, W_sh, W_oh, b_sh, b_oh,
                                            rel_emb, trel, AC, 2 * HD);
    rowdot3x2_kernel<<<BD * LD, 64, 0, stream>>>(AC, W_st, b_st, W_ot, b_ot,
                                                 out + 192, out + 3264);
}

// Round 4
// 198.739 us; speedup vs baseline: 2.3428x; 1.1418x over previous
//
#include <hip/hip_runtime.h>
#include <hip/hip_bf16.h>

// Problem dims (fixed): B=8, L=128, H=768, R=24
#define BD   8
#define LD   128
#define HD   768
#define RD   24
#define H2D  384
#define NF   1536   // fused N (two heads side by side)

typedef __attribute__((ext_vector_type(8))) short bf16x8;
typedef __attribute__((ext_vector_type(4))) float f32x4;

__device__ __forceinline__ short f2bf(float f) {
    __hip_bfloat16 h = __float2bfloat16(f);
    return *reinterpret_cast<short*>(&h);
}

// ---------------------------------------------------------------------------
// pool[b,h] = sum_l embed[b,l,h]*mask[b,l] / sum_l mask[b,l]
// grid (B, 12): block handles 64 h's, 4-way split over L. 256 threads.
__global__ void pool_kernel(const float* __restrict__ embed,
                            const float* __restrict__ mask,
                            float* __restrict__ pool) {
    __shared__ float mrow[LD];
    __shared__ float msum_sh;
    __shared__ float part[4][64];
    const int b = blockIdx.x, c = blockIdx.y, tid = threadIdx.x;
    if (tid < LD) mrow[tid] = mask[b * LD + tid];
    __syncthreads();
    if (tid == 0) {
        float s = 0.f;
        for (int l = 0; l < LD; ++l) s += mrow[l];
        msum_sh = s;
    }
    __syncthreads();
    const int lc = tid >> 6, hh = tid & 63;
    const int h = c * 64 + hh;
    float acc = 0.f;
    const float* base = embed + ((size_t)b * LD + lc * 32) * HD + h;
#pragma unroll 8
    for (int i = 0; i < 32; ++i) acc += base[(size_t)i * HD] * mrow[lc * 32 + i];
    part[lc][hh] = acc;
    __syncthreads();
    if (lc == 0) {
        float s = part[0][hh] + part[1][hh] + part[2][hh] + part[3][hh];
        pool[b * HD + h] = s / msum_sh;
    }
}

// ---------------------------------------------------------------------------
// rh[b,n] = relu(pool[b,:] @ W_hr[:,n] + b_hr[n])   grid (B, 6), 256 threads
__global__ void relh_kernel(const float* __restrict__ pool,
                            const float* __restrict__ W_hr, const float* __restrict__ b_hr,
                            float* __restrict__ rh) {
    __shared__ float prow[HD];
    __shared__ float part[4][64];
    const int b = blockIdx.x, c = blockIdx.y, tid = threadIdx.x;
    for (int k = tid; k < HD; k += 256) prow[k] = pool[b * HD + k];
    __syncthreads();
    const int kc = tid >> 6, nn = tid & 63;
    const int n = c * 64 + nn;
    float acc = 0.f;
#pragma unroll 8
    for (int i = 0; i < 192; ++i) {
        const int k = kc * 192 + i;
        acc += prow[k] * W_hr[(size_t)k * H2D + n];
    }
    part[kc][nn] = acc;
    __syncthreads();
    if (kc == 0)
        rh[b * H2D + n] = fmaxf(part[0][nn] + part[1][nn] + part[2][nn] + part[3][nn] + b_hr[n], 0.f);
}

// ---------------------------------------------------------------------------
// stage1[b,n] = rh[b,:] @ W_rj[:,n] + b_rj[n]   grid (B), 256 threads
__global__ void stage1_kernel(const float* __restrict__ rh,
                              const float* __restrict__ W_rj, const float* __restrict__ b_rj,
                              float* __restrict__ out) {
    __shared__ float rl[H2D];
    __shared__ float part[8][RD];
    const int b = blockIdx.x, tid = threadIdx.x;
    for (int k = tid; k < H2D; k += 256) rl[k] = rh[b * H2D + k];
    __syncthreads();
    if (tid < 192) {
        const int n = tid % 24, kc = tid / 24;
        float acc = 0.f;
#pragma unroll 8
        for (int i = 0; i < 48; ++i) {
            const int k = kc * 48 + i;
            acc += rl[k] * W_rj[k * RD + n];
        }
        part[kc][n] = acc;
    }
    __syncthreads();
    if (tid < RD) {
        float s = b_rj[tid];
#pragma unroll
        for (int q = 0; q < 8; ++q) s += part[q][tid];
        out[b * RD + tid] = s;
    }
}

// ---------------------------------------------------------------------------
// biasrel[b,n] = re[b,:] @ Wtop[:,n] + bias[n], n<768 -> W_sh/b_sh, else W_oh/b_oh
// grid (B, 12), 512 threads (4 kc x 128 n)
__global__ void relbias_kernel(const float* __restrict__ rel_emb, const int* __restrict__ trel,
                               const float* __restrict__ W_sh, const float* __restrict__ b_sh,
                               const float* __restrict__ W_oh, const float* __restrict__ b_oh,
                               float* __restrict__ biasrel) {
    __shared__ float re[HD];
    __shared__ float part[4][128];
    const int b = blockIdx.x, c = blockIdx.y, tid = threadIdx.x;
    const int rel = trel[b];
    for (int k = tid; k < HD; k += 512) re[k] = rel_emb[(size_t)rel * HD + k];
    __syncthreads();
    const int kc = tid >> 7, nn = tid & 127;
    const int n = c * 128 + nn;
    const float* Wp;
    const float* bb;
    int col;
    if (n < HD) { Wp = W_sh; bb = b_sh; col = n; }
    else        { Wp = W_oh; bb = b_oh; col = n - HD; }
    float acc = 0.f;
#pragma unroll 8
    for (int i = 0; i < 192; ++i) {
        const int k = kc * 192 + i;
        acc += re[k] * Wp[(size_t)k * HD + col];
    }
    part[kc][nn] = acc;
    __syncthreads();
    if (kc == 0)
        biasrel[b * NF + n] = part[0][nn] + part[1][nn] + part[2][nn] + part[3][nn] + bb[col];
}

// ---------------------------------------------------------------------------
// MFMA GEMM: out[m, 0:1536] = embed[m,:] @ [W0 | W1], K=768.
// 64x64 tile, 256 threads (4 waves, each 32x32).
// MODE 1 epilogue: relu(acc + biasrel[b, ncol])
template <int MODE>
__global__ __launch_bounds__(256) void mfma_gemm(
        const float* __restrict__ embed,
        const float* __restrict__ W0, const float* __restrict__ W1,
        const float* __restrict__ biasrel,
        float* __restrict__ out) {
    __shared__ __align__(16) short As[64][40];  // [m][k] bf16, pad 8
    __shared__ __align__(16) short Bs[64][40];  // [n][k] bf16 (W transposed), pad 8

    const int tid = threadIdx.x;
    const int bn0 = blockIdx.x * 64;
    const int bm0 = blockIdx.y * 64;

    const float* Wp;
    int col0;
    if (bn0 < HD) { Wp = W0; col0 = bn0; }
    else          { Wp = W1; col0 = bn0 - HD; }

    // staging indices
    const int am = tid >> 2;          // 0..63 (m row)
    const int ak = (tid & 3) * 4;     // 0,4,8,12
    const int bn = tid & 63;          // n row in Bs
    const int bk = (tid >> 6) * 8;    // 0,8,16,24

    // compute indices
    const int lane = tid & 63;
    const int wv = tid >> 6;
    const int wm = (wv >> 1) * 32;
    const int wn = (wv & 1) * 32;
    const int fr = lane & 15;
    const int kq = (lane >> 4) * 8;

    f32x4 acc00 = {0.f, 0.f, 0.f, 0.f}, acc01 = acc00, acc10 = acc00, acc11 = acc00;

    for (int kt = 0; kt < 24; ++kt) {
        const int k0 = kt << 5;
        const float* arow = embed + (size_t)(bm0 + am) * HD + k0;
        float4 va0 = *(const float4*)(arow + ak);
        float4 va1 = *(const float4*)(arow + ak + 16);
        float vb[8];
#pragma unroll
        for (int j = 0; j < 8; ++j)
            vb[j] = Wp[(size_t)(k0 + bk + j) * HD + col0 + bn];

        __syncthreads();  // previous tile fully consumed
        {
            short4 s0 = { f2bf(va0.x), f2bf(va0.y), f2bf(va0.z), f2bf(va0.w) };
            short4 s1 = { f2bf(va1.x), f2bf(va1.y), f2bf(va1.z), f2bf(va1.w) };
            *(short4*)&As[am][ak]      = s0;
            *(short4*)&As[am][ak + 16] = s1;
            bf16x8 pb;
#pragma unroll
            for (int j = 0; j < 8; ++j) pb[j] = f2bf(vb[j]);
            *(bf16x8*)&Bs[bn][bk] = pb;
        }
        __syncthreads();

        bf16x8 a0 = *(bf16x8*)&As[wm + fr][kq];
        bf16x8 a1 = *(bf16x8*)&As[wm + 16 + fr][kq];
        bf16x8 b0 = *(bf16x8*)&Bs[wn + fr][kq];
        bf16x8 b1 = *(bf16x8*)&Bs[wn + 16 + fr][kq];
        acc00 = __builtin_amdgcn_mfma_f32_16x16x32_bf16(a0, b0, acc00, 0, 0, 0);
        acc01 = __builtin_amdgcn_mfma_f32_16x16x32_bf16(a0, b1, acc01, 0, 0, 0);
        acc10 = __builtin_amdgcn_mfma_f32_16x16x32_bf16(a1, b0, acc10, 0, 0, 0);
        acc11 = __builtin_amdgcn_mfma_f32_16x16x32_bf16(a1, b1, acc11, 0, 0, 0);
    }

    // epilogue: C/D layout col=lane&15, row=(lane>>4)*4+reg  [m89/m91]
    const float* bp = nullptr;
    if (MODE) bp = biasrel + (size_t)(bm0 / LD) * NF;
    const int mq = (lane >> 4) * 4;
#pragma unroll
    for (int i = 0; i < 2; ++i) {
#pragma unroll
        for (int j = 0; j < 2; ++j) {
            f32x4 a = (i == 0) ? (j == 0 ? acc00 : acc01) : (j == 0 ? acc10 : acc11);
            const int ncol = bn0 + wn + j * 16 + fr;
#pragma unroll
            for (int r = 0; r < 4; ++r) {
                const int mrow = bm0 + wm + i * 16 + mq + r;
                float v = a[r];
                if (MODE) v = fmaxf(v + bp[ncol], 0.f);
                out[(size_t)mrow * NF + ncol] = v;
            }
        }
    }
}

// ---------------------------------------------------------------------------
// pred_corres[b,i,j] = sum_h relu(A[b,j,h] + C[b,i,h] + b_corr[h]) * W_gc[h] + b_gc
// AC buffer: row m=b*L+idx, A at cols [0,768), C at cols [768,1536)
__global__ void corres_kernel(const float* __restrict__ AC,
                              const float* __restrict__ b_corr, const float* __restrict__ W_gc,
                              const float* __restrict__ b_gc,
                              float* __restrict__ out) {
    const int b = blockIdx.y;
    const int i0 = blockIdx.x * 4;
    const int tid = threadIdx.x;
    const int lane = tid & 63;
    const int wave = tid >> 6;  // 0..3

    float wg[12], cb[4][12];
#pragma unroll
    for (int s = 0; s < 12; ++s) {
        const int h = lane + 64 * s;
        wg[s] = W_gc[h];
        const float bc = b_corr[h];
#pragma unroll
        for (int i = 0; i < 4; ++i)
            cb[i][s] = AC[((size_t)(b * LD + i0 + i)) * NF + HD + h] + bc;
    }
    const float bg = b_gc[0];

    for (int j = wave; j < LD; j += 4) {
        const float* arow = AC + ((size_t)(b * LD + j)) * NF;
        float a[12];
#pragma unroll
        for (int s = 0; s < 12; ++s) a[s] = arow[lane + 64 * s];
        float sum[4] = {0.f, 0.f, 0.f, 0.f};
#pragma unroll
        for (int s = 0; s < 12; ++s) {
#pragma unroll
            for (int i = 0; i < 4; ++i)
                sum[i] += fmaxf(a[s] + cb[i][s], 0.f) * wg[s];
        }
#pragma unroll
        for (int off = 32; off > 0; off >>= 1) {
#pragma unroll
            for (int i = 0; i < 4; ++i) sum[i] += __shfl_down(sum[i], off, 64);
        }
        if (lane == 0) {
#pragma unroll
            for (int i = 0; i < 4; ++i)
                out[((size_t)(b * LD + i0 + i)) * LD + j] = sum[i] + bg;
        }
    }
}

// ---------------------------------------------------------------------------
// subj[m,t] = H1[m,0:768]@W_st[:,t]+b_st[t]; obj[m,t] = H1[m,768:1536]@W_ot[:,t]+b_ot[t]
__global__ void rowdot3x2_kernel(const float* __restrict__ H1,
                                 const float* __restrict__ W_st, const float* __restrict__ b_st,
                                 const float* __restrict__ W_ot, const float* __restrict__ b_ot,
                                 float* __restrict__ out_subj, float* __restrict__ out_obj) {
    const int m = blockIdx.x;
    const int lane = threadIdx.x;  // 64
    float s[3] = {0.f, 0.f, 0.f}, o[3] = {0.f, 0.f, 0.f};
#pragma unroll
    for (int ss = 0; ss < 12; ++ss) {
        const int h = lane + 64 * ss;
        const float hs = H1[(size_t)m * NF + h];
        const float ho = H1[(size_t)m * NF + HD + h];
#pragma unroll
        for (int t = 0; t < 3; ++t) {
            s[t] += hs * W_st[h * 3 + t];
            o[t] += ho * W_ot[h * 3 + t];
        }
    }
    for (int off = 32; off > 0; off >>= 1) {
#pragma unroll
        for (int t = 0; t < 3; ++t) {
            s[t] += __shfl_down(s[t], off, 64);
            o[t] += __shfl_down(o[t], off, 64);
        }
    }
    if (lane == 0) {
#pragma unroll
        for (int t = 0; t < 3; ++t) {
            out_subj[m * 3 + t] = s[t] + b_st[t];
            out_obj[m * 3 + t]  = o[t] + b_ot[t];
        }
    }
}

// ---------------------------------------------------------------------------
extern "C" void kernel_launch(void* const* d_in, const int* in_sizes, int n_in,
                              void* d_out, int out_size, void* d_ws, size_t ws_size,
                              hipStream_t stream) {
    const float* embed   = (const float*)d_in[0];
    const float* mask    = (const float*)d_in[1];
    const int*   trel    = (const int*)d_in[2];
    const float* W_hr    = (const float*)d_in[3];
    const float* b_hr    = (const float*)d_in[4];
    const float* W_rj    = (const float*)d_in[5];
    const float* b_rj    = (const float*)d_in[6];
    const float* rel_emb = (const float*)d_in[7];
    const float* W_corr  = (const float*)d_in[8];
    const float* b_corr  = (const float*)d_in[9];
    const float* W_gc    = (const float*)d_in[10];
    const float* b_gc    = (const float*)d_in[11];
    const float* W_sh    = (const float*)d_in[12];
    const float* b_sh    = (const float*)d_in[13];
    const float* W_st    = (const float*)d_in[14];
    const float* b_st    = (const float*)d_in[15];
    const float* W_oh    = (const float*)d_in[16];
    const float* b_oh    = (const float*)d_in[17];
    const float* W_ot    = (const float*)d_in[18];
    const float* b_ot    = (const float*)d_in[19];
    float* out = (float*)d_out;

    float* ws      = (float*)d_ws;
    float* AC      = ws;                        // 1024*1536 = 1572864 floats (reused as H1)
    float* pool    = ws + 1572864;              // 6144
    float* rh      = ws + 1572864 + 6144;       // 3072
    float* biasrel = ws + 1572864 + 9216;       // 12288

    // Output layout: stage1[192] | subj[3072] | obj[3072] | pred_corres[131072]
    pool_kernel<<<dim3(BD, 12), 256, 0, stream>>>(embed, mask, pool);
    relh_kernel<<<dim3(BD, 6), 256, 0, stream>>>(pool, W_hr, b_hr, rh);
    stage1_kernel<<<BD, 256, 0, stream>>>(rh, W_rj, b_rj, out);
    relbias_kernel<<<dim3(BD, 12), 512, 0, stream>>>(rel_emb, trel, W_sh, b_sh, W_oh, b_oh, biasrel);

    dim3 ggrid(NF / 64, (BD * LD) / 64);  // (24, 16) = 384 blocks
    mfma_gemm<0><<<ggrid, 256, 0, stream>>>(embed, W_corr, W_corr + (size_t)HD * HD, nullptr, AC);
    corres_kernel<<<dim3(LD / 4, BD), 256, 0, stream>>>(AC, b_corr, W_gc, b_gc, out + 6336);

    mfma_gemm<1><<<ggrid, 256, 0, stream>>>(embed, W_sh + (size_t)HD * HD, W_oh + (size_t)HD * HD,
                                            biasrel, AC);
    rowdot3x2_kernel<<<BD * LD, 64, 0, stream>>>(AC, W_st, b_st, W_ot, b_ot,
                                                 out + 192, out + 3264);
}